// Round 17
// baseline (52.108 us; speedup 1.0000x reference)
//
#include <hip/hip_runtime.h>
#include <hip/hip_bf16.h>

// Problem: N=8, L=S=1024, C=256, H=8, D=32
// out = (v1 * softmax_S(q k^T / sqrt(D)) v2) @ Wp^T + bp
// Pipeline: wprep (weights f32->bf16 once) -> fused prep+proj
// (output-stationary, 64-row tiles, 4 waves x 64-col strips -> 2 blocks/CU
// so A-staging overlaps MFMA across blocks; W traffic unchanged) ->
// fused attn (register-resident P, 32-L waves, R16 best) ->
// out GEMM (output-stationary, R14 best).

typedef __bf16 bf16_t;
using bf16x8 = __attribute__((ext_vector_type(8))) __bf16;
using f32x4  = __attribute__((ext_vector_type(4))) float;

#define NB 8
#define LL 1024
#define SS 1024
#define CC 256
#define HH 8
#define DD 32
#define MTOK (NB * LL)   // 8192 tokens for both L-side and S-side

// 1/sqrt(D) * log2(e): softmax done in exp2 space, folded into Q at proj time
#define QSCALE (0.17677669529663688f * 1.4426950408889634f)

static __device__ __forceinline__ f32x4 mfma16(bf16x8 a, bf16x8 b, f32x4 c) {
  return __builtin_amdgcn_mfma_f32_16x16x32_bf16(a, b, c, 0, 0, 0);
}
static __device__ __forceinline__ float fexp2(float x) {
  return __builtin_amdgcn_exp2f(x);
}

// ---------------------------------------------------------------------------
// Kernel 1: weights f32 -> bf16 (tiny: 1 MB read, converted ONCE)
// ---------------------------------------------------------------------------
__global__ __launch_bounds__(256) void wprep_kernel(
    const float* __restrict__ wq, const float* __restrict__ wk,
    const float* __restrict__ wv, const float* __restrict__ wp,
    bf16_t* __restrict__ Wall) {
  const int i = blockIdx.x * 256 + threadIdx.x;  // 65536 float4
  const int w = i >> 14, j = i & 16383;
  const float4* src = (const float4*)(w == 0 ? wq : w == 1 ? wk : w == 2 ? wv : wp);
  float4 v = src[j];
  bf16_t t4[4] __attribute__((aligned(8))) = {(bf16_t)v.x, (bf16_t)v.y,
                                              (bf16_t)v.z, (bf16_t)v.w};
  *(uint2*)(Wall + (size_t)w * CC * CC + 4 * (size_t)j) = *(const uint2*)t4;
}

// ---------------------------------------------------------------------------
// Kernel 2: fused prep + merged projections (NT GEMM), OUTPUT-STATIONARY.
// 64-row tiles (grid (MTOK/64, 2) = 256 blocks — W L2 traffic unchanged),
// but 256 threads / 4 waves, each owning a 64-COL strip -> 2 blocks/CU:
// block B+1's A-staging (f32 HBM reads + barrier) overlaps block B's MFMA
// phase. R15's mistake was shrinking the TILE (2x blocks -> 2x W re-reads);
// this keeps the tile and halves the threads instead.
// z=0: A=x+xe -> Q (pre-scaled by QSCALE) and V1 (row-major).
// z=1: A=s1+se -> K (row-major) and V2T (transposed per head [n][h][d][s]).
// ---------------------------------------------------------------------------
__global__ __launch_bounds__(256) void proj_kernel(
    const float* __restrict__ x, const float* __restrict__ xe,
    const float* __restrict__ s1, const float* __restrict__ se,
    const bf16_t* __restrict__ Wall,
    bf16_t* __restrict__ Qw, bf16_t* __restrict__ Kw,
    bf16_t* __restrict__ V1w, bf16_t* __restrict__ V2T) {
  __shared__ __align__(16) bf16_t a_lds[64][264];  // 33 KB -> 2 blocks/CU

  const int tid = threadIdx.x;          // 0..255
  const int lane = tid & 63;
  const int wid = tid >> 6;             // 0..3: owns cols wid*64..wid*64+63
  const int r = lane & 15, g = lane >> 4;
  const int bm = blockIdx.x * 64;
  const int z = blockIdx.y;

  const float* A0 = z ? s1 : x;
  const float* A1 = z ? se : xe;
  const bf16_t* W0 = Wall + (size_t)z * CC * CC;  // z=0: Wq, z=1: Wk
  const bf16_t* W1 = Wall + 2 * (size_t)CC * CC;  // Wv

  // ---- stage A-tile: 64 rows x 256 cols, f32 add -> bf16 -> LDS (once)
#pragma unroll
  for (int i = 0; i < 16; ++i) {
    const int f = i * 256 + tid;        // float4 index in tile (4096 total)
    const int row = f >> 6, c4 = f & 63;
    float4 va = *(const float4*)(A0 + (size_t)(bm + row) * CC + c4 * 4);
    float4 vb = *(const float4*)(A1 + (size_t)(bm + row) * CC + c4 * 4);
    bf16_t t4[4] __attribute__((aligned(8))) = {
        (bf16_t)(va.x + vb.x), (bf16_t)(va.y + vb.y), (bf16_t)(va.z + vb.z),
        (bf16_t)(va.w + vb.w)};
    *(uint2*)&a_lds[row][c4 * 4] = *(const uint2*)t4;
  }
  __syncthreads();

  const int col_b0 = wid * 64;

  f32x4 acc0[4][4] = {};   // [row-frag 0..3][col-frag 0..3], W0 output
  f32x4 acc1[4][4] = {};   // W1 output
#pragma unroll
  for (int k0 = 0; k0 < CC; k0 += 32) {
    bf16x8 a[4];
#pragma unroll
    for (int i = 0; i < 4; ++i)
      a[i] = *(const bf16x8*)&a_lds[i * 16 + r][k0 + g * 8];
#pragma unroll
    for (int j = 0; j < 4; ++j) {
      bf16x8 b0 =
          *(const bf16x8*)(W0 + (size_t)(col_b0 + j * 16 + r) * CC + k0 + g * 8);
      bf16x8 b1 =
          *(const bf16x8*)(W1 + (size_t)(col_b0 + j * 16 + r) * CC + k0 + g * 8);
#pragma unroll
      for (int i = 0; i < 4; ++i) {
        acc0[i][j] = mfma16(a[i], b0, acc0[i][j]);
        acc1[i][j] = mfma16(a[i], b1, acc1[i][j]);
      }
    }
  }

#pragma unroll
  for (int i = 0; i < 4; ++i) {
#pragma unroll
    for (int j = 0; j < 4; ++j) {
      const int row_base = bm + i * 16 + g * 4;
      const int col = col_b0 + j * 16 + r;
      if (z == 0) {
#pragma unroll
        for (int t = 0; t < 4; ++t) {
          Qw[(size_t)(row_base + t) * CC + col] =
              (bf16_t)(acc0[i][j][t] * QSCALE);
          V1w[(size_t)(row_base + t) * CC + col] = (bf16_t)acc1[i][j][t];
        }
      } else {
#pragma unroll
        for (int t = 0; t < 4; ++t)
          Kw[(size_t)(row_base + t) * CC + col] = (bf16_t)acc0[i][j][t];
        // transposed per-head store: V2T[((n*H + h)*D + d)][s]
        const int n = row_base >> 10;
        const int s = row_base & (SS - 1);
        const int h = col >> 5;
        const int d = col & (DD - 1);
        bf16_t t4[4] __attribute__((aligned(8)));
#pragma unroll
        for (int t = 0; t < 4; ++t) t4[t] = (bf16_t)acc1[i][j][t];
        *(uint2*)(V2T + ((size_t)((n * HH + h) * DD + d)) * SS + s) =
            *(const uint2*)t4;
      }
    }
  }
}

// ---------------------------------------------------------------------------
// Kernel 3: fused flash attention + v1 gating — REGISTER-RESIDENT P,
// 32-L WAVES (R16 best-known, unchanged).
// Each wave owns 32 L-rows (2 Q frags): one K-fragment read feeds 2 QK
// MFMAs, PV V-fragments shared by both L-halves -> ds_reads halved vs 16-L.
// Block = 8 waves x 32 L = 256 L-rows, 512 thr, grid 256.
// Sigma-permuted K staging (v(s) = (s&96)|((s&4)<<2)|((s&24)>>1)|(s&3))
// keeps P entirely in registers: QK tile m covers s-rows
// 32(m>>1)+8g+4(m&1)+reg, so tiles (2t,2t+1) ARE the PV B-fragment.
// XCD swizzle: work=(bid&7)*32+(bid>>3) (bijective, 256 blocks).
// Unnormalized exp2 softmax (M=0 safe: |t| <~ 20 vs overflow at 128).
// ---------------------------------------------------------------------------
__global__ __launch_bounds__(512) void attn_kernel(
    const bf16_t* __restrict__ Qw, const bf16_t* __restrict__ Kw,
    const bf16_t* __restrict__ V1w, const bf16_t* __restrict__ V2T,
    bf16_t* __restrict__ MSG) {
  __shared__ __align__(16) bf16_t k_lds[2][128][40];   // [buf][vperm][d] 20 KB
  __shared__ __align__(16) bf16_t v_lds[2][32][136];   // [buf][d][s+8]  17 KB

  const int tid = threadIdx.x;
  const int lane = tid & 63;
  const int wid = tid >> 6;  // 0..7, owns L-rows l0+wid*32..+32
  const int r = lane & 15, g = lane >> 4;

  // XCD-aware bijective swizzle (256 blocks, 8 XCDs, 32 blocks/XCD)
  const int bid = blockIdx.x;
  const int work = (bid & 7) * 32 + (bid >> 3);
  const int grp = work >> 2;          // (n,h) group, 0..63
  const int lt = work & 3;            // L-tile (256 rows) within group
  const int n = grp >> 3;
  const int h = grp & 7;
  const int l0 = lt * 256;
  const size_t tokQ = (size_t)n * LL + l0 + wid * 32;  // wave's 32 L-rows

  // two Q fragments (B-operand of swapped QK^T); Q pre-scaled by QSCALE
  const bf16x8 qf0 = *(const bf16x8*)(Qw + (tokQ + r) * CC + h * DD + g * 8);
  const bf16x8 qf1 =
      *(const bf16x8*)(Qw + (tokQ + 16 + r) * CC + h * DD + g * 8);
  const bf16_t* Kb = Kw + ((size_t)n * SS) * CC + h * DD;
  const bf16_t* Vt = V2T + ((size_t)(n * HH + h)) * DD * SS;

  // staging (512 threads): K one uint4 each (128 rows x 4 quads), V one
  // uint4 each (32 rows x 16 quads). K rows stored sigma-PERMUTED.
  const int ktr = tid >> 2, ktq = tid & 3;
  const int kpr = (ktr & 96) | ((ktr & 4) << 2) | ((ktr & 24) >> 1) | (ktr & 3);
  const int vtr = tid >> 4, vtq = tid & 15;

  float lr0 = 0.f, lr1 = 0.f;     // lane-local unnormalized denominators
  const f32x4 zero = {0.f, 0.f, 0.f, 0.f};
  f32x4 o00 = zero, o01 = zero;   // l = r:    d lo / d hi
  f32x4 o10 = zero, o11 = zero;   // l = 16+r: d lo / d hi

  // prologue: stage chunk 0
  uint4 kra = *(const uint4*)(Kb + (size_t)ktr * CC + ktq * 8);
  uint4 vra = *(const uint4*)(Vt + (size_t)vtr * SS + vtq * 8);
  *(uint4*)&k_lds[0][kpr][ktq * 8] = kra;
  *(uint4*)&v_lds[0][vtr][vtq * 8] = vra;
  __syncthreads();

  for (int c = 0; c < 8; ++c) {
    const int cur = c & 1;
    // ---- issue next chunk's global loads early (hide under compute)
    if (c < 7) {
      const int s1 = (c + 1) * 128;
      kra = *(const uint4*)(Kb + (size_t)(s1 + ktr) * CC + ktq * 8);
      vra = *(const uint4*)(Vt + (size_t)vtr * SS + s1 + vtq * 8);
    }

    // ---- QK^T: 8 K-fragment reads feed 16 MFMAs (2 L-halves)
    f32x4 pt0[8], pt1[8];
#pragma unroll
    for (int m = 0; m < 8; ++m) {
      bf16x8 kf = *(const bf16x8*)&k_lds[cur][m * 16 + r][g * 8];
      pt0[m] = mfma16(kf, qf0, zero);  // s-rows 32(m>>1)+8g+4(m&1)+reg, l=r
      pt1[m] = mfma16(kf, qf1, zero);  //                               l=16+r
    }

    // ---- softmax (unnormalized) + PV; P in registers, V frags shared
#pragma unroll
    for (int t = 0; t < 4; ++t) {
      float a0 = fexp2(pt0[2 * t][0]), a1 = fexp2(pt0[2 * t][1]);
      float a2 = fexp2(pt0[2 * t][2]), a3 = fexp2(pt0[2 * t][3]);
      float a4 = fexp2(pt0[2 * t + 1][0]), a5 = fexp2(pt0[2 * t + 1][1]);
      float a6 = fexp2(pt0[2 * t + 1][2]), a7 = fexp2(pt0[2 * t + 1][3]);
      float b0 = fexp2(pt1[2 * t][0]), b1 = fexp2(pt1[2 * t][1]);
      float b2 = fexp2(pt1[2 * t][2]), b3 = fexp2(pt1[2 * t][3]);
      float b4 = fexp2(pt1[2 * t + 1][0]), b5 = fexp2(pt1[2 * t + 1][1]);
      float b6 = fexp2(pt1[2 * t + 1][2]), b7 = fexp2(pt1[2 * t + 1][3]);
      lr0 += ((a0 + a1) + (a2 + a3)) + ((a4 + a5) + (a6 + a7));
      lr1 += ((b0 + b1) + (b2 + b3)) + ((b4 + b5) + (b6 + b7));
      bf16_t pa[8] __attribute__((aligned(16))) = {
          (bf16_t)a0, (bf16_t)a1, (bf16_t)a2, (bf16_t)a3,
          (bf16_t)a4, (bf16_t)a5, (bf16_t)a6, (bf16_t)a7};
      bf16_t pb[8] __attribute__((aligned(16))) = {
          (bf16_t)b0, (bf16_t)b1, (bf16_t)b2, (bf16_t)b3,
          (bf16_t)b4, (bf16_t)b5, (bf16_t)b6, (bf16_t)b7};
      bf16x8 pf0 = *(const bf16x8*)pa;  // B[k=g*8+j][l=r],    s-slice 32t..
      bf16x8 pf1 = *(const bf16x8*)pb;  // B[k=g*8+j][l=16+r]
      bf16x8 va = *(const bf16x8*)&v_lds[cur][r][t * 32 + g * 8];
      bf16x8 vb = *(const bf16x8*)&v_lds[cur][16 + r][t * 32 + g * 8];
      o00 = mfma16(va, pf0, o00);
      o01 = mfma16(vb, pf0, o01);
      o10 = mfma16(va, pf1, o10);
      o11 = mfma16(vb, pf1, o11);
    }

    // ---- write next chunk into the other buffer
    if (c < 7) {
      *(uint4*)&k_lds[cur ^ 1][kpr][ktq * 8] = kra;
      *(uint4*)&v_lds[cur ^ 1][vtr][vtq * 8] = vra;
    }
    __syncthreads();
  }

  // ---- l reductions across the 4 g-groups sharing each l-column
  lr0 += __shfl_xor(lr0, 16);
  lr0 += __shfl_xor(lr0, 32);
  lr1 += __shfl_xor(lr1, 16);
  lr1 += __shfl_xor(lr1, 32);
  const float li0 = 1.f / lr0, li1 = 1.f / lr1;

  // ---- epilogue: V1 gate + store. lane owns l = r and l = 16+r.
  const bf16_t* V1b0 = V1w + (tokQ + r) * CC + h * DD;
  const bf16_t* V1b1 = V1w + (tokQ + 16 + r) * CC + h * DD;
  bf16_t* Mb0 = MSG + (tokQ + r) * CC + h * DD;
  bf16_t* Mb1 = MSG + (tokQ + 16 + r) * CC + h * DD;
  uint2 u00 = *(const uint2*)(V1b0 + g * 4);
  uint2 u01 = *(const uint2*)(V1b0 + 16 + g * 4);
  uint2 u10 = *(const uint2*)(V1b1 + g * 4);
  uint2 u11 = *(const uint2*)(V1b1 + 16 + g * 4);
  const bf16_t* v00 = (const bf16_t*)&u00;
  const bf16_t* v01 = (const bf16_t*)&u01;
  const bf16_t* v10 = (const bf16_t*)&u10;
  const bf16_t* v11 = (const bf16_t*)&u11;
  bf16_t w00[4] __attribute__((aligned(8))), w01[4] __attribute__((aligned(8)));
  bf16_t w10[4] __attribute__((aligned(8))), w11[4] __attribute__((aligned(8)));
#pragma unroll
  for (int i = 0; i < 4; ++i) {
    w00[i] = (bf16_t)(o00[i] * li0 * (float)v00[i]);
    w01[i] = (bf16_t)(o01[i] * li0 * (float)v01[i]);
    w10[i] = (bf16_t)(o10[i] * li1 * (float)v10[i]);
    w11[i] = (bf16_t)(o11[i] * li1 * (float)v11[i]);
  }
  *(uint2*)(Mb0 + g * 4) = *(const uint2*)w00;
  *(uint2*)(Mb0 + 16 + g * 4) = *(const uint2*)w01;
  *(uint2*)(Mb1 + g * 4) = *(const uint2*)w10;
  *(uint2*)(Mb1 + 16 + g * 4) = *(const uint2*)w11;
}

// ---------------------------------------------------------------------------
// Kernel 4: out = MSG @ Wp^T + bp   (f32 output), OUTPUT-STATIONARY.
// (R14 best-known: grid MTOK/64 = 128 blocks, 512 threads.)
// ---------------------------------------------------------------------------
__global__ __launch_bounds__(512) void out_kernel(
    const bf16_t* __restrict__ MSG, const bf16_t* __restrict__ Wp,
    const float* __restrict__ bp, float* __restrict__ out) {
  __shared__ __align__(16) bf16_t a_lds[64][264];  // 33 KB

  const int tid = threadIdx.x;
  const int lane = tid & 63;
  const int wid = tid >> 6;             // 0..7: owns cols wid*32..+31
  const int r = lane & 15, g = lane >> 4;
  const int bm = blockIdx.x * 64;

  // ---- stage MSG tile (bf16 copy): 2048 x 16B
#pragma unroll
  for (int i = 0; i < 4; ++i) {
    const int f = i * 512 + tid;        // uint4 index (2048 total)
    const int row = f >> 5, c8 = f & 31;
    uint4 v = *(const uint4*)(MSG + (size_t)(bm + row) * CC + c8 * 8);
    *(uint4*)&a_lds[row][c8 * 8] = v;
  }
  __syncthreads();

  const int col_b0 = wid * 32;

  f32x4 acc[4][2] = {};
#pragma unroll
  for (int k0 = 0; k0 < CC; k0 += 32) {
    bf16x8 a[4];
#pragma unroll
    for (int i = 0; i < 4; ++i)
      a[i] = *(const bf16x8*)&a_lds[i * 16 + r][k0 + g * 8];
    bf16x8 b0 = *(const bf16x8*)(Wp + (size_t)(col_b0 + r) * CC + k0 + g * 8);
    bf16x8 b1 = *(const bf16x8*)(Wp + (size_t)(col_b0 + 16 + r) * CC + k0 + g * 8);
#pragma unroll
    for (int i = 0; i < 4; ++i) {
      acc[i][0] = mfma16(a[i], b0, acc[i][0]);
      acc[i][1] = mfma16(a[i], b1, acc[i][1]);
    }
  }

#pragma unroll
  for (int i = 0; i < 4; ++i) {
#pragma unroll
    for (int j = 0; j < 2; ++j) {
      const int row_base = bm + i * 16 + g * 4;
      const int col = col_b0 + j * 16 + r;
      const float bv = bp[col];
#pragma unroll
      for (int t = 0; t < 4; ++t)
        out[(size_t)(row_base + t) * CC + col] = acc[i][j][t] + bv;
    }
  }
}

// ---------------------------------------------------------------------------
extern "C" void kernel_launch(void* const* d_in, const int* in_sizes, int n_in,
                              void* d_out, int out_size, void* d_ws,
                              size_t ws_size, hipStream_t stream) {
  const float* x  = (const float*)d_in[0];
  const float* s1 = (const float*)d_in[1];
  const float* xe = (const float*)d_in[2];
  const float* se = (const float*)d_in[3];
  const float* Wq = (const float*)d_in[4];
  const float* Wk = (const float*)d_in[5];
  const float* Wv = (const float*)d_in[6];
  const float* Wp = (const float*)d_in[7];
  const float* bp = (const float*)d_in[8];
  float* out = (float*)d_out;

  char* ws = (char*)d_ws;
  bf16_t* Wall = (bf16_t*)(ws);                     // 512 KB: Wq,Wk,Wv,Wp bf16
  bf16_t* Qw   = (bf16_t*)(ws + (1u << 20));        // 4 MB (pre-scaled)
  bf16_t* Kw   = (bf16_t*)(ws + (5u << 20));        // 4 MB
  bf16_t* V1w  = (bf16_t*)(ws + (9u << 20));        // 4 MB
  bf16_t* V2T  = (bf16_t*)(ws + (13u << 20));       // 4 MB [n][h][d][s]
  bf16_t* MSG  = (bf16_t*)(ws + (17u << 20));       // 4 MB
  bf16_t* Wpb  = Wall + 3 * CC * CC;

  wprep_kernel<<<256, 256, 0, stream>>>(Wq, Wk, Wv, Wp, Wall);
  proj_kernel<<<dim3(MTOK / 64, 2), 256, 0, stream>>>(
      x, xe, s1, se, Wall, Qw, Kw, V1w, V2T);
  attn_kernel<<<256, 512, 0, stream>>>(Qw, Kw, V1w, V2T, MSG);
  out_kernel<<<MTOK / 64, 512, 0, stream>>>(MSG, Wpb, bp, out);
}

// Round 18
// 48.578 us; speedup vs baseline: 1.0727x; 1.0727x over previous
//
#include <hip/hip_runtime.h>
#include <hip/hip_bf16.h>

// Problem: N=8, L=S=1024, C=256, H=8, D=32
// out = (v1 * softmax_S(q k^T / sqrt(D)) v2) @ Wp^T + bp
// Pipeline: wprep (weights f32->bf16 once) -> fused prep+proj
// (output-stationary, 64-row tiles, 8 waves x 32-col strips — R16 best) ->
// fused attn (register-resident P, 32-L waves — R16 best) ->
// out GEMM (output-stationary, 32-ROW tiles x 8 waves x 32-col strips:
// full CU coverage with the proven-good low-VGPR wave shape).

typedef __bf16 bf16_t;
using bf16x8 = __attribute__((ext_vector_type(8))) __bf16;
using f32x4  = __attribute__((ext_vector_type(4))) float;

#define NB 8
#define LL 1024
#define SS 1024
#define CC 256
#define HH 8
#define DD 32
#define MTOK (NB * LL)   // 8192 tokens for both L-side and S-side

// 1/sqrt(D) * log2(e): softmax done in exp2 space, folded into Q at proj time
#define QSCALE (0.17677669529663688f * 1.4426950408889634f)

static __device__ __forceinline__ f32x4 mfma16(bf16x8 a, bf16x8 b, f32x4 c) {
  return __builtin_amdgcn_mfma_f32_16x16x32_bf16(a, b, c, 0, 0, 0);
}
static __device__ __forceinline__ float fexp2(float x) {
  return __builtin_amdgcn_exp2f(x);
}

// ---------------------------------------------------------------------------
// Kernel 1: weights f32 -> bf16 (tiny: 1 MB read, converted ONCE)
// ---------------------------------------------------------------------------
__global__ __launch_bounds__(256) void wprep_kernel(
    const float* __restrict__ wq, const float* __restrict__ wk,
    const float* __restrict__ wv, const float* __restrict__ wp,
    bf16_t* __restrict__ Wall) {
  const int i = blockIdx.x * 256 + threadIdx.x;  // 65536 float4
  const int w = i >> 14, j = i & 16383;
  const float4* src = (const float4*)(w == 0 ? wq : w == 1 ? wk : w == 2 ? wv : wp);
  float4 v = src[j];
  bf16_t t4[4] __attribute__((aligned(8))) = {(bf16_t)v.x, (bf16_t)v.y,
                                              (bf16_t)v.z, (bf16_t)v.w};
  *(uint2*)(Wall + (size_t)w * CC * CC + 4 * (size_t)j) = *(const uint2*)t4;
}

// ---------------------------------------------------------------------------
// Kernel 2: fused prep + merged projections (NT GEMM), OUTPUT-STATIONARY.
// (R16 best-known: 64-row tiles, 512 threads, 8 waves x 32-col strips.
// R15/R17 both showed 64-col strips regress: VGPR cliff + 2x W-frag loads.)
// A-tile (64 x 256) = f32(x+xe | s1+se) -> bf16 staged in LDS ONCE; each of
// the 8 waves owns a 32-col output strip and computes ALL 64 rows for BOTH
// weight matrices.
// z=0: A=x+xe -> Q (pre-scaled by QSCALE) and V1 (row-major).
// z=1: A=s1+se -> K (row-major) and V2T (transposed per head [n][h][d][s]).
// ---------------------------------------------------------------------------
__global__ __launch_bounds__(512) void proj_kernel(
    const float* __restrict__ x, const float* __restrict__ xe,
    const float* __restrict__ s1, const float* __restrict__ se,
    const bf16_t* __restrict__ Wall,
    bf16_t* __restrict__ Qw, bf16_t* __restrict__ Kw,
    bf16_t* __restrict__ V1w, bf16_t* __restrict__ V2T) {
  __shared__ __align__(16) bf16_t a_lds[64][264];  // 33 KB

  const int tid = threadIdx.x;          // 0..511
  const int lane = tid & 63;
  const int wid = tid >> 6;             // 0..7: owns cols wid*32..wid*32+31
  const int r = lane & 15, g = lane >> 4;
  const int bm = blockIdx.x * 64;
  const int z = blockIdx.y;

  const float* A0 = z ? s1 : x;
  const float* A1 = z ? se : xe;
  const bf16_t* W0 = Wall + (size_t)z * CC * CC;  // z=0: Wq, z=1: Wk
  const bf16_t* W1 = Wall + 2 * (size_t)CC * CC;  // Wv

  // ---- stage A-tile: 64 rows x 256 cols, f32 add -> bf16 -> LDS (once)
#pragma unroll
  for (int i = 0; i < 8; ++i) {
    const int f = i * 512 + tid;        // float4 index in tile (4096 total)
    const int row = f >> 6, c4 = f & 63;
    float4 va = *(const float4*)(A0 + (size_t)(bm + row) * CC + c4 * 4);
    float4 vb = *(const float4*)(A1 + (size_t)(bm + row) * CC + c4 * 4);
    bf16_t t4[4] __attribute__((aligned(8))) = {
        (bf16_t)(va.x + vb.x), (bf16_t)(va.y + vb.y), (bf16_t)(va.z + vb.z),
        (bf16_t)(va.w + vb.w)};
    *(uint2*)&a_lds[row][c4 * 4] = *(const uint2*)t4;
  }
  __syncthreads();

  const int col_b0 = wid * 32;

  f32x4 acc0[4][2] = {};   // [row-frag 0..3][col-frag 0..1], W0 output
  f32x4 acc1[4][2] = {};   // W1 output
#pragma unroll
  for (int k0 = 0; k0 < CC; k0 += 32) {
    bf16x8 a[4];
#pragma unroll
    for (int i = 0; i < 4; ++i)
      a[i] = *(const bf16x8*)&a_lds[i * 16 + r][k0 + g * 8];
    bf16x8 b00 = *(const bf16x8*)(W0 + (size_t)(col_b0 + r) * CC + k0 + g * 8);
    bf16x8 b01 = *(const bf16x8*)(W0 + (size_t)(col_b0 + 16 + r) * CC + k0 + g * 8);
    bf16x8 b10 = *(const bf16x8*)(W1 + (size_t)(col_b0 + r) * CC + k0 + g * 8);
    bf16x8 b11 = *(const bf16x8*)(W1 + (size_t)(col_b0 + 16 + r) * CC + k0 + g * 8);
#pragma unroll
    for (int i = 0; i < 4; ++i) {
      acc0[i][0] = mfma16(a[i], b00, acc0[i][0]);
      acc0[i][1] = mfma16(a[i], b01, acc0[i][1]);
      acc1[i][0] = mfma16(a[i], b10, acc1[i][0]);
      acc1[i][1] = mfma16(a[i], b11, acc1[i][1]);
    }
  }

#pragma unroll
  for (int i = 0; i < 4; ++i) {
#pragma unroll
    for (int j = 0; j < 2; ++j) {
      const int row_base = bm + i * 16 + g * 4;
      const int col = col_b0 + j * 16 + r;
      if (z == 0) {
#pragma unroll
        for (int t = 0; t < 4; ++t) {
          Qw[(size_t)(row_base + t) * CC + col] =
              (bf16_t)(acc0[i][j][t] * QSCALE);
          V1w[(size_t)(row_base + t) * CC + col] = (bf16_t)acc1[i][j][t];
        }
      } else {
#pragma unroll
        for (int t = 0; t < 4; ++t)
          Kw[(size_t)(row_base + t) * CC + col] = (bf16_t)acc0[i][j][t];
        // transposed per-head store: V2T[((n*H + h)*D + d)][s]
        const int n = row_base >> 10;
        const int s = row_base & (SS - 1);
        const int h = col >> 5;
        const int d = col & (DD - 1);
        bf16_t t4[4] __attribute__((aligned(8)));
#pragma unroll
        for (int t = 0; t < 4; ++t) t4[t] = (bf16_t)acc1[i][j][t];
        *(uint2*)(V2T + ((size_t)((n * HH + h) * DD + d)) * SS + s) =
            *(const uint2*)t4;
      }
    }
  }
}

// ---------------------------------------------------------------------------
// Kernel 3: fused flash attention + v1 gating — REGISTER-RESIDENT P,
// 32-L WAVES (R16 best-known, unchanged).
// Each wave owns 32 L-rows (2 Q frags): one K-fragment read feeds 2 QK
// MFMAs, PV V-fragments shared by both L-halves -> ds_reads halved vs 16-L.
// Block = 8 waves x 32 L = 256 L-rows, 512 thr, grid 256.
// Sigma-permuted K staging (v(s) = (s&96)|((s&4)<<2)|((s&24)>>1)|(s&3))
// keeps P entirely in registers: QK tile m covers s-rows
// 32(m>>1)+8g+4(m&1)+reg, so tiles (2t,2t+1) ARE the PV B-fragment.
// XCD swizzle: work=(bid&7)*32+(bid>>3) (bijective, 256 blocks).
// Unnormalized exp2 softmax (M=0 safe: |t| <~ 20 vs overflow at 128).
// ---------------------------------------------------------------------------
__global__ __launch_bounds__(512) void attn_kernel(
    const bf16_t* __restrict__ Qw, const bf16_t* __restrict__ Kw,
    const bf16_t* __restrict__ V1w, const bf16_t* __restrict__ V2T,
    bf16_t* __restrict__ MSG) {
  __shared__ __align__(16) bf16_t k_lds[2][128][40];   // [buf][vperm][d] 20 KB
  __shared__ __align__(16) bf16_t v_lds[2][32][136];   // [buf][d][s+8]  17 KB

  const int tid = threadIdx.x;
  const int lane = tid & 63;
  const int wid = tid >> 6;  // 0..7, owns L-rows l0+wid*32..+32
  const int r = lane & 15, g = lane >> 4;

  // XCD-aware bijective swizzle (256 blocks, 8 XCDs, 32 blocks/XCD)
  const int bid = blockIdx.x;
  const int work = (bid & 7) * 32 + (bid >> 3);
  const int grp = work >> 2;          // (n,h) group, 0..63
  const int lt = work & 3;            // L-tile (256 rows) within group
  const int n = grp >> 3;
  const int h = grp & 7;
  const int l0 = lt * 256;
  const size_t tokQ = (size_t)n * LL + l0 + wid * 32;  // wave's 32 L-rows

  // two Q fragments (B-operand of swapped QK^T); Q pre-scaled by QSCALE
  const bf16x8 qf0 = *(const bf16x8*)(Qw + (tokQ + r) * CC + h * DD + g * 8);
  const bf16x8 qf1 =
      *(const bf16x8*)(Qw + (tokQ + 16 + r) * CC + h * DD + g * 8);
  const bf16_t* Kb = Kw + ((size_t)n * SS) * CC + h * DD;
  const bf16_t* Vt = V2T + ((size_t)(n * HH + h)) * DD * SS;

  // staging (512 threads): K one uint4 each (128 rows x 4 quads), V one
  // uint4 each (32 rows x 16 quads). K rows stored sigma-PERMUTED.
  const int ktr = tid >> 2, ktq = tid & 3;
  const int kpr = (ktr & 96) | ((ktr & 4) << 2) | ((ktr & 24) >> 1) | (ktr & 3);
  const int vtr = tid >> 4, vtq = tid & 15;

  float lr0 = 0.f, lr1 = 0.f;     // lane-local unnormalized denominators
  const f32x4 zero = {0.f, 0.f, 0.f, 0.f};
  f32x4 o00 = zero, o01 = zero;   // l = r:    d lo / d hi
  f32x4 o10 = zero, o11 = zero;   // l = 16+r: d lo / d hi

  // prologue: stage chunk 0
  uint4 kra = *(const uint4*)(Kb + (size_t)ktr * CC + ktq * 8);
  uint4 vra = *(const uint4*)(Vt + (size_t)vtr * SS + vtq * 8);
  *(uint4*)&k_lds[0][kpr][ktq * 8] = kra;
  *(uint4*)&v_lds[0][vtr][vtq * 8] = vra;
  __syncthreads();

  for (int c = 0; c < 8; ++c) {
    const int cur = c & 1;
    // ---- issue next chunk's global loads early (hide under compute)
    if (c < 7) {
      const int s1 = (c + 1) * 128;
      kra = *(const uint4*)(Kb + (size_t)(s1 + ktr) * CC + ktq * 8);
      vra = *(const uint4*)(Vt + (size_t)vtr * SS + s1 + vtq * 8);
    }

    // ---- QK^T: 8 K-fragment reads feed 16 MFMAs (2 L-halves)
    f32x4 pt0[8], pt1[8];
#pragma unroll
    for (int m = 0; m < 8; ++m) {
      bf16x8 kf = *(const bf16x8*)&k_lds[cur][m * 16 + r][g * 8];
      pt0[m] = mfma16(kf, qf0, zero);  // s-rows 32(m>>1)+8g+4(m&1)+reg, l=r
      pt1[m] = mfma16(kf, qf1, zero);  //                               l=16+r
    }

    // ---- softmax (unnormalized) + PV; P in registers, V frags shared
#pragma unroll
    for (int t = 0; t < 4; ++t) {
      float a0 = fexp2(pt0[2 * t][0]), a1 = fexp2(pt0[2 * t][1]);
      float a2 = fexp2(pt0[2 * t][2]), a3 = fexp2(pt0[2 * t][3]);
      float a4 = fexp2(pt0[2 * t + 1][0]), a5 = fexp2(pt0[2 * t + 1][1]);
      float a6 = fexp2(pt0[2 * t + 1][2]), a7 = fexp2(pt0[2 * t + 1][3]);
      float b0 = fexp2(pt1[2 * t][0]), b1 = fexp2(pt1[2 * t][1]);
      float b2 = fexp2(pt1[2 * t][2]), b3 = fexp2(pt1[2 * t][3]);
      float b4 = fexp2(pt1[2 * t + 1][0]), b5 = fexp2(pt1[2 * t + 1][1]);
      float b6 = fexp2(pt1[2 * t + 1][2]), b7 = fexp2(pt1[2 * t + 1][3]);
      lr0 += ((a0 + a1) + (a2 + a3)) + ((a4 + a5) + (a6 + a7));
      lr1 += ((b0 + b1) + (b2 + b3)) + ((b4 + b5) + (b6 + b7));
      bf16_t pa[8] __attribute__((aligned(16))) = {
          (bf16_t)a0, (bf16_t)a1, (bf16_t)a2, (bf16_t)a3,
          (bf16_t)a4, (bf16_t)a5, (bf16_t)a6, (bf16_t)a7};
      bf16_t pb[8] __attribute__((aligned(16))) = {
          (bf16_t)b0, (bf16_t)b1, (bf16_t)b2, (bf16_t)b3,
          (bf16_t)b4, (bf16_t)b5, (bf16_t)b6, (bf16_t)b7};
      bf16x8 pf0 = *(const bf16x8*)pa;  // B[k=g*8+j][l=r],    s-slice 32t..
      bf16x8 pf1 = *(const bf16x8*)pb;  // B[k=g*8+j][l=16+r]
      bf16x8 va = *(const bf16x8*)&v_lds[cur][r][t * 32 + g * 8];
      bf16x8 vb = *(const bf16x8*)&v_lds[cur][16 + r][t * 32 + g * 8];
      o00 = mfma16(va, pf0, o00);
      o01 = mfma16(vb, pf0, o01);
      o10 = mfma16(va, pf1, o10);
      o11 = mfma16(vb, pf1, o11);
    }

    // ---- write next chunk into the other buffer
    if (c < 7) {
      *(uint4*)&k_lds[cur ^ 1][kpr][ktq * 8] = kra;
      *(uint4*)&v_lds[cur ^ 1][vtr][vtq * 8] = vra;
    }
    __syncthreads();
  }

  // ---- l reductions across the 4 g-groups sharing each l-column
  lr0 += __shfl_xor(lr0, 16);
  lr0 += __shfl_xor(lr0, 32);
  lr1 += __shfl_xor(lr1, 16);
  lr1 += __shfl_xor(lr1, 32);
  const float li0 = 1.f / lr0, li1 = 1.f / lr1;

  // ---- epilogue: V1 gate + store. lane owns l = r and l = 16+r.
  const bf16_t* V1b0 = V1w + (tokQ + r) * CC + h * DD;
  const bf16_t* V1b1 = V1w + (tokQ + 16 + r) * CC + h * DD;
  bf16_t* Mb0 = MSG + (tokQ + r) * CC + h * DD;
  bf16_t* Mb1 = MSG + (tokQ + 16 + r) * CC + h * DD;
  uint2 u00 = *(const uint2*)(V1b0 + g * 4);
  uint2 u01 = *(const uint2*)(V1b0 + 16 + g * 4);
  uint2 u10 = *(const uint2*)(V1b1 + g * 4);
  uint2 u11 = *(const uint2*)(V1b1 + 16 + g * 4);
  const bf16_t* v00 = (const bf16_t*)&u00;
  const bf16_t* v01 = (const bf16_t*)&u01;
  const bf16_t* v10 = (const bf16_t*)&u10;
  const bf16_t* v11 = (const bf16_t*)&u11;
  bf16_t w00[4] __attribute__((aligned(8))), w01[4] __attribute__((aligned(8)));
  bf16_t w10[4] __attribute__((aligned(8))), w11[4] __attribute__((aligned(8)));
#pragma unroll
  for (int i = 0; i < 4; ++i) {
    w00[i] = (bf16_t)(o00[i] * li0 * (float)v00[i]);
    w01[i] = (bf16_t)(o01[i] * li0 * (float)v01[i]);
    w10[i] = (bf16_t)(o10[i] * li1 * (float)v10[i]);
    w11[i] = (bf16_t)(o11[i] * li1 * (float)v11[i]);
  }
  *(uint2*)(Mb0 + g * 4) = *(const uint2*)w00;
  *(uint2*)(Mb0 + 16 + g * 4) = *(const uint2*)w01;
  *(uint2*)(Mb1 + g * 4) = *(const uint2*)w10;
  *(uint2*)(Mb1 + 16 + g * 4) = *(const uint2*)w11;
}

// ---------------------------------------------------------------------------
// Kernel 4: out = MSG @ Wp^T + bp   (f32 output), OUTPUT-STATIONARY.
// 32-ROW tiles, 256 blocks x 512 threads: full CU coverage (R14's 128
// blocks left half the chip idle) while KEEPING the proven 8-wave x 32-col
// strip shape (acc[2][2], 2 W-frag loads/k-step — R15/R17 showed 64-col
// strips regress). MSG still read exactly once; Wp L2 16->32 MB (cheap).
// ---------------------------------------------------------------------------
__global__ __launch_bounds__(512) void out_kernel(
    const bf16_t* __restrict__ MSG, const bf16_t* __restrict__ Wp,
    const float* __restrict__ bp, float* __restrict__ out) {
  __shared__ __align__(16) bf16_t a_lds[32][264];  // 16.5 KB

  const int tid = threadIdx.x;
  const int lane = tid & 63;
  const int wid = tid >> 6;             // 0..7: owns cols wid*32..+31
  const int r = lane & 15, g = lane >> 4;
  const int bm = blockIdx.x * 32;

  // ---- stage MSG tile (bf16 copy): 1024 x 16B
#pragma unroll
  for (int i = 0; i < 2; ++i) {
    const int f = i * 512 + tid;        // uint4 index (1024 total)
    const int row = f >> 5, c8 = f & 31;
    uint4 v = *(const uint4*)(MSG + (size_t)(bm + row) * CC + c8 * 8);
    *(uint4*)&a_lds[row][c8 * 8] = v;
  }
  __syncthreads();

  const int col_b0 = wid * 32;

  f32x4 acc[2][2] = {};
#pragma unroll
  for (int k0 = 0; k0 < CC; k0 += 32) {
    bf16x8 a[2];
#pragma unroll
    for (int i = 0; i < 2; ++i)
      a[i] = *(const bf16x8*)&a_lds[i * 16 + r][k0 + g * 8];
    bf16x8 b0 = *(const bf16x8*)(Wp + (size_t)(col_b0 + r) * CC + k0 + g * 8);
    bf16x8 b1 = *(const bf16x8*)(Wp + (size_t)(col_b0 + 16 + r) * CC + k0 + g * 8);
#pragma unroll
    for (int i = 0; i < 2; ++i) {
      acc[i][0] = mfma16(a[i], b0, acc[i][0]);
      acc[i][1] = mfma16(a[i], b1, acc[i][1]);
    }
  }

#pragma unroll
  for (int i = 0; i < 2; ++i) {
#pragma unroll
    for (int j = 0; j < 2; ++j) {
      const int row_base = bm + i * 16 + g * 4;
      const int col = col_b0 + j * 16 + r;
      const float bv = bp[col];
#pragma unroll
      for (int t = 0; t < 4; ++t)
        out[(size_t)(row_base + t) * CC + col] = acc[i][j][t] + bv;
    }
  }
}

// ---------------------------------------------------------------------------
extern "C" void kernel_launch(void* const* d_in, const int* in_sizes, int n_in,
                              void* d_out, int out_size, void* d_ws,
                              size_t ws_size, hipStream_t stream) {
  const float* x  = (const float*)d_in[0];
  const float* s1 = (const float*)d_in[1];
  const float* xe = (const float*)d_in[2];
  const float* se = (const float*)d_in[3];
  const float* Wq = (const float*)d_in[4];
  const float* Wk = (const float*)d_in[5];
  const float* Wv = (const float*)d_in[6];
  const float* Wp = (const float*)d_in[7];
  const float* bp = (const float*)d_in[8];
  float* out = (float*)d_out;

  char* ws = (char*)d_ws;
  bf16_t* Wall = (bf16_t*)(ws);                     // 512 KB: Wq,Wk,Wv,Wp bf16
  bf16_t* Qw   = (bf16_t*)(ws + (1u << 20));        // 4 MB (pre-scaled)
  bf16_t* Kw   = (bf16_t*)(ws + (5u << 20));        // 4 MB
  bf16_t* V1w  = (bf16_t*)(ws + (9u << 20));        // 4 MB
  bf16_t* V2T  = (bf16_t*)(ws + (13u << 20));       // 4 MB [n][h][d][s]
  bf16_t* MSG  = (bf16_t*)(ws + (17u << 20));       // 4 MB
  bf16_t* Wpb  = Wall + 3 * CC * CC;

  wprep_kernel<<<256, 256, 0, stream>>>(Wq, Wk, Wv, Wp, Wall);
  proj_kernel<<<dim3(MTOK / 64, 2), 512, 0, stream>>>(
      x, xe, s1, se, Wall, Qw, Kw, V1w, V2T);
  attn_kernel<<<256, 512, 0, stream>>>(Qw, Kw, V1w, V2T, MSG);
  out_kernel<<<MTOK / 32, 512, 0, stream>>>(MSG, Wpb, bp, out);
}